// Round 4
// baseline (336.535 us; speedup 1.0000x reference)
//
#include <hip/hip_runtime.h>
#include <math.h>

#define BATCH 8
#define LSEQ  8192
#define HD    256
#define PD    256
#define CHUNK 64
#define NC    128
#define MROWS 65536

typedef short bf16x8 __attribute__((ext_vector_type(8)));
typedef float f32x4  __attribute__((ext_vector_type(4)));
typedef unsigned short u16;
typedef unsigned int   u32;

__device__ __forceinline__ void async16(void* l, const void* g) {
    __builtin_amdgcn_global_load_lds((const __attribute__((address_space(1))) void*)g,
                                     (__attribute__((address_space(3))) void*)l, 16, 0, 0);
}

__device__ __forceinline__ u16 bf_rne(float f) {
    unsigned u = __float_as_uint(f);
    return (u16)((u + 0x7FFFu + ((u >> 16) & 1u)) >> 16);
}

// swizzled element offset within a [128 rows][64 cols] bf16 tile (8192 elems)
__device__ __forceinline__ int swz(int r, int c) {
    return r * 64 + (c ^ ((r & 7) << 3));
}

// ---------------- K0a: per-p discretization + A-power table ----------------
__global__ void k_setup(const float* __restrict__ lre_, const float* __restrict__ lim_,
                        const float* __restrict__ lstep,
                        float* __restrict__ coefRe, float* __restrict__ coefIm,
                        float* __restrict__ ApowRe, float* __restrict__ ApowIm) {
    int p = threadIdx.x;
    float lre = lre_[p], lim = lim_[p];
    float dt = expf(lstep[p]);
    float er = lre * dt, ei = lim * dt;               // Lam * Delta
    float ex = expf(er);
    float abr = ex * cosf(ei), abi = ex * sinf(ei);   // Lambda_bar
    float nr = abr - 1.0f, ni = abi;
    float den = lre * lre + lim * lim;
    coefRe[p] = (nr * lre + ni * lim) / den;
    coefIm[p] = (ni * lre - nr * lim) / den;
    for (int j = 0; j <= CHUNK; ++j) {
        float exr = expf(er * (float)j);
        ApowRe[j * PD + p] = exr * cosf(ei * (float)j);
        ApowIm[j * PD + p] = exr * sinf(ei * (float)j);
    }
}

// ---- K0b: Bcat[512 n][256 k] bf16 hi/lo, tile-blocked (4x4 tiles) + swizzled ----
// row 2p = re(B_bar), row 2p+1 = im(B_bar)
__global__ void k_bbar(const float* __restrict__ B_ri,
                       const float* __restrict__ coefRe, const float* __restrict__ coefIm,
                       u16* __restrict__ BcH, u16* __restrict__ BcL) {
    int p = blockIdx.x, h = threadIdx.x;
    float cr = coefRe[p], ci = coefIm[p];
    float br = B_ri[((size_t)p * HD + h) * 2 + 0];
    float bi = B_ri[((size_t)p * HD + h) * 2 + 1];
    float re = cr * br - ci * bi;
    float im = cr * bi + ci * br;
    unsigned ur = __float_as_uint(re) & 0xFFFF0000u;
    unsigned ui = __float_as_uint(im) & 0xFFFF0000u;
    int n = 2 * p;
    int tile = ((n >> 7) * 4 + (h >> 6)) * 8192;
    int ri_ = tile + swz(n & 127, h & 63);
    int ii_ = tile + swz((n + 1) & 127, h & 63);
    BcH[ri_] = (u16)(ur >> 16);
    BcL[ri_] = bf_rne(re - __uint_as_float(ur));
    BcH[ii_] = (u16)(ui >> 16);
    BcL[ii_] = bf_rne(im - __uint_as_float(ui));
}

// ---- K0c: Ccat[256 n][512 k] bf16 hi/lo, tile-blocked (2x8 tiles) + swizzled ----
// col 2p = Cre, col 2p+1 = -Cim
__global__ void k_ccat(const float* __restrict__ Cre, const float* __restrict__ Cim,
                       u16* __restrict__ CcH, u16* __restrict__ CcL) {
    int h = blockIdx.x, p = threadIdx.x;
    float re = Cre[(size_t)h * PD + p];
    float im = -Cim[(size_t)h * PD + p];
    unsigned ur = __float_as_uint(re) & 0xFFFF0000u;
    unsigned ui = __float_as_uint(im) & 0xFFFF0000u;
    int tile = ((h >> 7) * 8 + (p >> 5)) * 8192;
    int c0 = (2 * p) & 63;
    int ri_ = tile + swz(h & 127, c0);
    int ii_ = ri_ + 1;                    // c0 even; swizzle preserves bit 0
    CcH[ri_] = (u16)(ur >> 16);
    CcL[ri_] = bf_rne(re - __uint_as_float(ur));
    CcH[ii_] = (u16)(ui >> 16);
    CcL[ii_] = bf_rne(im - __uint_as_float(ui));
}

// ---------------- G1: X = sig @ Bcat^T  (split A 3-product), out = XbH/XbL ----------
// 128x128 tile, BK=64, 4 waves (2x2), 16x16x32 MFMA; output blocked bf16 hi/lo pairs.
__global__ __launch_bounds__(256, 2) void gemm1(const float* __restrict__ A,
        const u16* __restrict__ Bh, const u16* __restrict__ Bl,
        u32* __restrict__ XH, u32* __restrict__ XL) {
    __shared__ u16 AhS[8192];
    __shared__ u16 AlS[8192];
    __shared__ u16 BhS[8192];
    __shared__ u16 BlS[8192];

    int nwg = gridDim.x;
    int bid = blockIdx.x;
    int w = (bid & 7) * (nwg >> 3) + (bid >> 3);   // bijective XCD swizzle
    int nt = w & 3, mt = w >> 2;
    int m0 = mt * 128, n0 = nt * 128;
    int t = threadIdx.x;
    int l = t & 63;
    int wv = t >> 6;
    int wm = wv & 1, wn = wv >> 1;
    int lr = l & 15, kg = l >> 4;
    int sx = (lr & 7) << 3;

    f32x4 acc[4][4] = {};

    for (int k0 = 0; k0 < HD; k0 += 64) {
        int tb = ((n0 >> 7) * 4 + (k0 >> 6)) * 8192;
        #pragma unroll
        for (int i = 0; i < 4; ++i) {
            int lb = i * 2048 + (t & 0xC0) * 8;
            async16(&BhS[lb], &Bh[tb + (i * 256 + t) * 8]);
            async16(&BlS[lb], &Bl[tb + (i * 256 + t) * 8]);
        }
        #pragma unroll
        for (int i = 0; i < 8; ++i) {
            int idx = i * 1024 + t * 4;
            int r = idx >> 6, c = idx & 63;
            int so = swz(r, c);
            float4 v = *(const float4*)&A[(size_t)(m0 + r) * HD + k0 + c];
            unsigned u0 = __float_as_uint(v.x) & 0xFFFF0000u;
            unsigned u1 = __float_as_uint(v.y) & 0xFFFF0000u;
            unsigned u2 = __float_as_uint(v.z) & 0xFFFF0000u;
            unsigned u3 = __float_as_uint(v.w) & 0xFFFF0000u;
            *(ushort4*)&AhS[so] = make_ushort4((u16)(u0 >> 16), (u16)(u1 >> 16),
                                               (u16)(u2 >> 16), (u16)(u3 >> 16));
            *(ushort4*)&AlS[so] = make_ushort4(
                bf_rne(v.x - __uint_as_float(u0)), bf_rne(v.y - __uint_as_float(u1)),
                bf_rne(v.z - __uint_as_float(u2)), bf_rne(v.w - __uint_as_float(u3)));
        }
        __syncthreads();
        #pragma unroll
        for (int kk = 0; kk < 2; ++kk) {
            int ko = kk * 32 + kg * 8;
            bf16x8 ah[4], al[4], bh[4], bl[4];
            #pragma unroll
            for (int i = 0; i < 4; ++i) {
                int ro = (wm * 64 + i * 16 + lr) * 64 + (ko ^ sx);
                ah[i] = *(const bf16x8*)&AhS[ro];
                al[i] = *(const bf16x8*)&AlS[ro];
            }
            #pragma unroll
            for (int j = 0; j < 4; ++j) {
                int ro = (wn * 64 + j * 16 + lr) * 64 + (ko ^ sx);
                bh[j] = *(const bf16x8*)&BhS[ro];
                bl[j] = *(const bf16x8*)&BlS[ro];
            }
            #pragma unroll
            for (int i = 0; i < 4; ++i)
                #pragma unroll
                for (int j = 0; j < 4; ++j) {
                    acc[i][j] = __builtin_amdgcn_mfma_f32_16x16x32_bf16(ah[i], bh[j], acc[i][j], 0, 0, 0);
                    acc[i][j] = __builtin_amdgcn_mfma_f32_16x16x32_bf16(ah[i], bl[j], acc[i][j], 0, 0, 0);
                    acc[i][j] = __builtin_amdgcn_mfma_f32_16x16x32_bf16(al[i], bh[j], acc[i][j], 0, 0, 0);
                }
        }
        __syncthreads();
    }
    // epilogue: pair re/im across adjacent lanes, write packed hi (even lane) / lo (odd)
    bool evenlane = !(lr & 1);
    #pragma unroll
    for (int i = 0; i < 4; ++i) {
        #pragma unroll
        for (int j = 0; j < 4; ++j) {
            int col = n0 + wn * 64 + j * 16 + lr;
            int pcol = col & ~1;
            int kt = pcol >> 6;
            int ce2 = (pcol & 63) * 2;                // byte offset in row, pre-swizzle
            #pragma unroll
            for (int q = 0; q < 4; ++q) {
                int m = m0 + wm * 64 + i * 16 + kg * 4 + q;
                float v = acc[i][j][q];
                float pv = __shfl_xor(v, 1, 64);
                float re = evenlane ? v : pv;
                float im = evenlane ? pv : v;
                unsigned ur = __float_as_uint(re) & 0xFFFF0000u;
                unsigned ui = __float_as_uint(im) & 0xFFFF0000u;
                int tile = (m >> 7) * 8 + kt;
                int widx = tile * 4096 + (m & 127) * 32 + ((ce2 ^ ((m & 7) << 4)) >> 2);
                if (evenlane) {
                    XH[widx] = ui | (ur >> 16);
                } else {
                    float lre = re - __uint_as_float(ur);
                    float lim = im - __uint_as_float(ui);
                    XL[widx] = ((u32)bf_rne(lim) << 16) | bf_rne(lre);
                }
            }
        }
    }
}

// ---------------- P1: chunk-end states (read XbH+XbL blocked) ----------------
__global__ __launch_bounds__(256) void k_ends(const u32* __restrict__ XH, const u32* __restrict__ XL,
        const float* __restrict__ ApowRe, const float* __restrict__ ApowIm,
        float* __restrict__ ends) {
    int p = threadIdx.x;
    int c = blockIdx.x & (NC - 1), b = blockIdx.x >> 7;
    float ar = ApowRe[PD + p], ai = ApowIm[PD + p];    // A^1
    float xr = 0.f, xi = 0.f;
    int tile = (b * 64 + (c >> 1)) * 8 + (p >> 5);
    int mlo = (c & 1) * 64;
    int ce2 = (4 * p) & 127;
    int base = tile * 4096 + mlo * 32;
    #pragma unroll 8
    for (int i = 0; i < CHUNK; ++i) {
        int widx = base + i * 32 + ((ce2 ^ ((i & 7) << 4)) >> 2);
        u32 h = XH[widx], lo = XL[widx];
        float ur = __uint_as_float(h << 16) + __uint_as_float(lo << 16);
        float uim = __uint_as_float(h & 0xFFFF0000u) + __uint_as_float(lo & 0xFFFF0000u);
        float nr = fmaf(ar, xr, fmaf(-ai, xi, ur));
        float ni = fmaf(ar, xi, fmaf(ai, xr, uim));
        xr = nr; xi = ni;
    }
    *(float2*)&ends[((size_t)(b * NC + c)) * 512 + 2 * p] = make_float2(xr, xi);
}

// ---------------- P2: carry scan over chunks (in-place -> exclusive) ----------------
__global__ void k_scan2(float* __restrict__ ends,
                        const float* __restrict__ ApowRe, const float* __restrict__ ApowIm) {
    int p = threadIdx.x, b = blockIdx.x;
    float Ar = ApowRe[CHUNK * PD + p], Ai = ApowIm[CHUNK * PD + p];  // A^CHUNK
    float cr = 0.f, ci = 0.f;
    #pragma unroll 4
    for (int c = 0; c < NC; ++c) {
        size_t idx = ((size_t)(b * NC + c)) * 512 + 2 * p;
        float2 e = *(const float2*)&ends[idx];
        *(float2*)&ends[idx] = make_float2(cr, ci);
        float nr = fmaf(Ar, cr, fmaf(-Ai, ci, e.x));
        float ni = fmaf(Ar, ci, fmaf(Ai, cr, e.y));
        cr = nr; ci = ni;
    }
}

// ---------------- P3: recompute scan with carry, overwrite XbH with bf16(state) ---------
__global__ __launch_bounds__(256) void k_scan3(u32* __restrict__ XH, const u32* __restrict__ XL,
        const float* __restrict__ ApowRe, const float* __restrict__ ApowIm,
        const float* __restrict__ carry) {
    int p = threadIdx.x;
    int c = blockIdx.x & (NC - 1), b = blockIdx.x >> 7;
    float ar = ApowRe[PD + p], ai = ApowIm[PD + p];    // A^1
    float2 cv = *(const float2*)&carry[((size_t)(b * NC + c)) * 512 + 2 * p];
    float xr = cv.x, xi = cv.y;
    int tile = (b * 64 + (c >> 1)) * 8 + (p >> 5);
    int mlo = (c & 1) * 64;
    int ce2 = (4 * p) & 127;
    int base = tile * 4096 + mlo * 32;
    #pragma unroll 8
    for (int i = 0; i < CHUNK; ++i) {
        int widx = base + i * 32 + ((ce2 ^ ((i & 7) << 4)) >> 2);
        u32 h = XH[widx], lo = XL[widx];
        float ur = __uint_as_float(h << 16) + __uint_as_float(lo << 16);
        float uim = __uint_as_float(h & 0xFFFF0000u) + __uint_as_float(lo & 0xFFFF0000u);
        float nr = fmaf(ar, xr, fmaf(-ai, xi, ur));
        float ni = fmaf(ar, xi, fmaf(ai, xr, uim));
        xr = nr; xi = ni;
        XH[widx] = ((u32)bf_rne(xi) << 16) | bf_rne(xr);
    }
}

// ---------------- G2: y = Xbf @ Ccat^T + D*u   (A plain, B split, 2 products) ----------
__global__ __launch_bounds__(256, 3) void gemm2(const u16* __restrict__ Ah,
        const u16* __restrict__ Bh, const u16* __restrict__ Bl,
        const float* __restrict__ Dvec, const float* __restrict__ sig,
        float* __restrict__ y) {
    __shared__ u16 AhS[8192];
    __shared__ u16 BhS[8192];
    __shared__ u16 BlS[8192];

    int nwg = gridDim.x;
    int bid = blockIdx.x;
    int w = (bid & 7) * (nwg >> 3) + (bid >> 3);
    int nt = w & 1, mt = w >> 1;
    int m0 = mt * 128, n0 = nt * 128;
    int t = threadIdx.x;
    int l = t & 63;
    int wv = t >> 6;
    int wm = wv & 1, wn = wv >> 1;
    int lr = l & 15, kg = l >> 4;
    int sx = (lr & 7) << 3;

    f32x4 acc[4][4] = {};

    for (int k0 = 0; k0 < 512; k0 += 64) {
        int ta = ((m0 >> 7) * 8 + (k0 >> 6)) * 8192;
        int tb = ((n0 >> 7) * 8 + (k0 >> 6)) * 8192;
        #pragma unroll
        for (int i = 0; i < 4; ++i) {
            int lb = i * 2048 + (t & 0xC0) * 8;
            async16(&AhS[lb], &Ah[ta + (i * 256 + t) * 8]);
            async16(&BhS[lb], &Bh[tb + (i * 256 + t) * 8]);
            async16(&BlS[lb], &Bl[tb + (i * 256 + t) * 8]);
        }
        __syncthreads();
        #pragma unroll
        for (int kk = 0; kk < 2; ++kk) {
            int ko = kk * 32 + kg * 8;
            bf16x8 ah[4], bh[4], bl[4];
            #pragma unroll
            for (int i = 0; i < 4; ++i) {
                int ro = (wm * 64 + i * 16 + lr) * 64 + (ko ^ sx);
                ah[i] = *(const bf16x8*)&AhS[ro];
            }
            #pragma unroll
            for (int j = 0; j < 4; ++j) {
                int ro = (wn * 64 + j * 16 + lr) * 64 + (ko ^ sx);
                bh[j] = *(const bf16x8*)&BhS[ro];
                bl[j] = *(const bf16x8*)&BlS[ro];
            }
            #pragma unroll
            for (int i = 0; i < 4; ++i)
                #pragma unroll
                for (int j = 0; j < 4; ++j) {
                    acc[i][j] = __builtin_amdgcn_mfma_f32_16x16x32_bf16(ah[i], bh[j], acc[i][j], 0, 0, 0);
                    acc[i][j] = __builtin_amdgcn_mfma_f32_16x16x32_bf16(ah[i], bl[j], acc[i][j], 0, 0, 0);
                }
        }
        __syncthreads();
    }
    #pragma unroll
    for (int i = 0; i < 4; ++i) {
        #pragma unroll
        for (int j = 0; j < 4; ++j) {
            int n = n0 + wn * 64 + j * 16 + lr;
            float dn = Dvec[n];
            #pragma unroll
            for (int q = 0; q < 4; ++q) {
                int m = m0 + wm * 64 + i * 16 + kg * 4 + q;
                y[(size_t)m * HD + n] = acc[i][j][q] + dn * sig[(size_t)m * HD + n];
            }
        }
    }
}

// ---------------- launcher ----------------
extern "C" void kernel_launch(void* const* d_in, const int* in_sizes, int n_in,
                              void* d_out, int out_size, void* d_ws, size_t ws_size,
                              hipStream_t stream) {
    const float* sig   = (const float*)d_in[0];
    const float* lre   = (const float*)d_in[1];
    const float* lim   = (const float*)d_in[2];
    const float* B_ri  = (const float*)d_in[3];
    const float* Cre   = (const float*)d_in[4];
    const float* Cim   = (const float*)d_in[5];
    const float* Dv    = (const float*)d_in[6];
    const float* lstep = (const float*)d_in[7];
    float* y = (float*)d_out;
    (void)in_sizes; (void)n_in; (void)out_size; (void)ws_size;

    char* base = (char*)d_ws;
    u32*  XH     = (u32*)base;  base += (size_t)MROWS * 256 * 4;      // 64 MB (packed re|im)
    u32*  XL     = (u32*)base;  base += (size_t)MROWS * 256 * 4;      // 64 MB
    float* ends   = (float*)base; base += (size_t)BATCH * NC * 512 * 4; // 2 MB
    float* ApowRe = (float*)base; base += (size_t)(CHUNK + 1) * PD * 4;
    float* ApowIm = (float*)base; base += (size_t)(CHUNK + 1) * PD * 4;
    float* coefRe = (float*)base; base += PD * 4;
    float* coefIm = (float*)base; base += PD * 4;
    u16*  BcH    = (u16*)base;  base += (size_t)512 * HD * 2;
    u16*  BcL    = (u16*)base;  base += (size_t)512 * HD * 2;
    u16*  CcH    = (u16*)base;  base += (size_t)HD * 512 * 2;
    u16*  CcL    = (u16*)base;  base += (size_t)HD * 512 * 2;

    k_setup<<<dim3(1), dim3(PD), 0, stream>>>(lre, lim, lstep, coefRe, coefIm, ApowRe, ApowIm);
    k_bbar<<<dim3(PD), dim3(HD), 0, stream>>>(B_ri, coefRe, coefIm, BcH, BcL);
    k_ccat<<<dim3(HD), dim3(PD), 0, stream>>>(Cre, Cim, CcH, CcL);
    gemm1<<<dim3(2048), dim3(256), 0, stream>>>(sig, BcH, BcL, XH, XL);
    k_ends<<<dim3(NC * BATCH), dim3(PD), 0, stream>>>(XH, XL, ApowRe, ApowIm, ends);
    k_scan2<<<dim3(BATCH), dim3(PD), 0, stream>>>(ends, ApowRe, ApowIm);
    k_scan3<<<dim3(NC * BATCH), dim3(PD), 0, stream>>>(XH, XL, ApowRe, ApowIm, ends);
    gemm2<<<dim3(1024), dim3(256), 0, stream>>>((const u16*)XH, CcH, CcL, Dv, sig, y);
}

// Round 5
// 281.260 us; speedup vs baseline: 1.1965x; 1.1965x over previous
//
#include <hip/hip_runtime.h>
#include <math.h>

#define BATCH 8
#define LSEQ  8192
#define HD    256
#define PD    256
#define CHUNK 64
#define NC    128
#define MROWS 65536

typedef _Float16 f16x8 __attribute__((ext_vector_type(8)));
typedef float    f32x4 __attribute__((ext_vector_type(4)));
typedef unsigned int u32;

__device__ __forceinline__ void async16(void* l, const void* g) {
    __builtin_amdgcn_global_load_lds((const __attribute__((address_space(1))) void*)g,
                                     (__attribute__((address_space(3))) void*)l, 16, 0, 0);
}

// Blocked fp16 layout: matrix [R rows][K cols] as tiles of [256][32];
// element (r,k) -> ((r>>8)*KT + (k>>5))*8192 + (r&255)*32 + (k&31), KT = K/32.

// ---------------- K0a: per-p discretization + A-power table ----------------
__global__ void k_setup(const float* __restrict__ lre_, const float* __restrict__ lim_,
                        const float* __restrict__ lstep,
                        float* __restrict__ coefRe, float* __restrict__ coefIm,
                        float* __restrict__ ApowRe, float* __restrict__ ApowIm) {
    int p = threadIdx.x;
    float lre = lre_[p], lim = lim_[p];
    float dt = expf(lstep[p]);
    float er = lre * dt, ei = lim * dt;               // Lam * Delta
    float ex = expf(er);
    float abr = ex * cosf(ei), abi = ex * sinf(ei);   // Lambda_bar
    float nr = abr - 1.0f, ni = abi;
    float den = lre * lre + lim * lim;
    coefRe[p] = (nr * lre + ni * lim) / den;
    coefIm[p] = (ni * lre - nr * lim) / den;
    for (int j = 0; j <= CHUNK; ++j) {
        float exr = expf(er * (float)j);
        ApowRe[j * PD + p] = exr * cosf(ei * (float)j);
        ApowIm[j * PD + p] = exr * sinf(ei * (float)j);
    }
}

// ---- K0b: Bcat[512 n][256 k] fp16 blocked; row 2p = re(B_bar), 2p+1 = im ----
__global__ void k_bbar(const float* __restrict__ B_ri,
                       const float* __restrict__ coefRe, const float* __restrict__ coefIm,
                       _Float16* __restrict__ Bc) {
    int p = blockIdx.x, h = threadIdx.x;
    float cr = coefRe[p], ci = coefIm[p];
    float br = B_ri[((size_t)p * HD + h) * 2 + 0];
    float bi = B_ri[((size_t)p * HD + h) * 2 + 1];
    float re = cr * br - ci * bi;
    float im = cr * bi + ci * br;
    int n = 2 * p;
    size_t t0 = ((size_t)(n >> 8) * 8 + (h >> 5)) * 8192;
    Bc[t0 + (size_t)(n & 255) * 32 + (h & 31)]       = (_Float16)re;
    Bc[t0 + (size_t)((n + 1) & 255) * 32 + (h & 31)] = (_Float16)im;
}

// ---- K0c: Ccat[256 h][512 k] fp16 blocked; col 2p = Cre, 2p+1 = -Cim ----
__global__ void k_ccat(const float* __restrict__ Cre, const float* __restrict__ Cim,
                       _Float16* __restrict__ Cc) {
    int h = blockIdx.x, p = threadIdx.x;
    int k = 2 * p;
    size_t t0 = (size_t)(k >> 5) * 8192 + (size_t)h * 32;
    Cc[t0 + (k & 31)]     = (_Float16)Cre[(size_t)h * PD + p];
    Cc[t0 + (k & 31) + 1] = (_Float16)(-Cim[(size_t)h * PD + p]);
}

// ---- prepass: sig fp32 row-major -> fp16 blocked [mb][kb] tiles [256][32] ----
__global__ __launch_bounds__(256) void k_sigh(const float* __restrict__ sig,
                                              _Float16* __restrict__ out) {
    size_t e = (size_t)blockIdx.x * 256 + threadIdx.x;   // one float4 per thread
    size_t m = e >> 6; int c4 = (int)(e & 63);
    float4 v = *(const float4*)&sig[m * 256 + (size_t)c4 * 4];
    int kb = c4 >> 3, c = (c4 & 7) * 4;
    _Float16 h4[4] = {(_Float16)v.x, (_Float16)v.y, (_Float16)v.z, (_Float16)v.w};
    *(ushort4*)&out[((m >> 8) * 8 + kb) * 8192 + (m & 255) * 32 + c] = *(ushort4*)h4;
}

// ---------------- fp16 MFMA GEMM: out[M][N] = A[M][K] * B[N][K]^T ----------------
// BM=BN=256, BK=32, 512 thr (8 waves 2Mx4N), wave-tile 128x64.
// 4-slot LDS rotation, prefetch depth 3, counted vmcnt(12), raw s_barrier, setprio.
template<int KT, int NTB, bool EPI>
__global__ __launch_bounds__(512, 2) void gemm_f16(
        const _Float16* __restrict__ Ag, const _Float16* __restrict__ Bg,
        _Float16* __restrict__ Xout,
        float* __restrict__ yout, const float* __restrict__ Dvec,
        const float* __restrict__ sig) {
    __shared__ _Float16 LA[4][8192];
    __shared__ _Float16 LB[4][8192];

    int nwg = gridDim.x;
    int bid = blockIdx.x;
    int w = (bid & 7) * (nwg >> 3) + (bid >> 3);   // bijective XCD swizzle (nwg%8==0)
    int nb = w % NTB, mb = w / NTB;
    int t = threadIdx.x;
    int wv = t >> 6, l = t & 63;
    int wm = wv & 1, wn = wv >> 1;                  // 2 x 4 waves
    int lr = l & 15, kg = l >> 4;
    const size_t abase = (size_t)mb * KT * 8192;
    const size_t bbase = (size_t)nb * KT * 8192;

    f32x4 acc[8][4] = {};

    auto STAGE = [&](int kt) {
        int buf = kt & 3;
        int o = t * 8;
        const _Float16* ag = &Ag[abase + (size_t)kt * 8192];
        const _Float16* bg = &Bg[bbase + (size_t)kt * 8192];
        async16(&LA[buf][o],        &ag[o]);
        async16(&LA[buf][o + 4096], &ag[o + 4096]);
        async16(&LB[buf][o],        &bg[o]);
        async16(&LB[buf][o + 4096], &bg[o + 4096]);
    };
    STAGE(0); STAGE(1); STAGE(2);

    #pragma unroll
    for (int kt = 0; kt < KT; ++kt) {
        int buf = kt & 3;
        if (kt + 3 < KT) {
            STAGE(kt + 3);
            asm volatile("s_waitcnt vmcnt(12)" ::: "memory");
        } else if (kt + 2 < KT) {
            asm volatile("s_waitcnt vmcnt(8)" ::: "memory");
        } else if (kt + 1 < KT) {
            asm volatile("s_waitcnt vmcnt(4)" ::: "memory");
        } else {
            asm volatile("s_waitcnt vmcnt(0)" ::: "memory");
        }
        __builtin_amdgcn_s_barrier();

        f16x8 af[8], bf[4];
        #pragma unroll
        for (int i = 0; i < 8; ++i)
            af[i] = *(const f16x8*)&LA[buf][(wm * 128 + i * 16 + lr) * 32 + kg * 8];
        #pragma unroll
        for (int j = 0; j < 4; ++j)
            bf[j] = *(const f16x8*)&LB[buf][(wn * 64 + j * 16 + lr) * 32 + kg * 8];

        __builtin_amdgcn_s_setprio(1);
        #pragma unroll
        for (int i = 0; i < 8; ++i)
            #pragma unroll
            for (int j = 0; j < 4; ++j)
                acc[i][j] = __builtin_amdgcn_mfma_f32_16x16x32_f16(af[i], bf[j], acc[i][j], 0, 0, 0);
        __builtin_amdgcn_s_setprio(0);
        __builtin_amdgcn_s_barrier();
    }

    // epilogue: C/D frag layout col = lane&15, row = (lane>>4)*4 + q
    if constexpr (!EPI) {
        // write X fp16 blocked [mb][16 k-tiles]; X col = n
        #pragma unroll
        for (int j = 0; j < 4; ++j) {
            int n = nb * 256 + wn * 64 + j * 16 + lr;
            size_t tb = ((size_t)mb * 16 + (n >> 5)) * 8192 + (n & 31);
            #pragma unroll
            for (int i = 0; i < 8; ++i)
                #pragma unroll
                for (int q = 0; q < 4; ++q) {
                    int r = wm * 128 + i * 16 + kg * 4 + q;
                    Xout[tb + (size_t)r * 32] = (_Float16)acc[i][j][q];
                }
        }
    } else {
        #pragma unroll
        for (int j = 0; j < 4; ++j) {
            int n = wn * 64 + j * 16 + lr;
            float dn = Dvec[n];
            #pragma unroll
            for (int i = 0; i < 8; ++i)
                #pragma unroll
                for (int q = 0; q < 4; ++q) {
                    int r = wm * 128 + i * 16 + kg * 4 + q;
                    size_t m = (size_t)mb * 256 + r;
                    yout[m * 256 + n] = acc[i][j][q] + dn * sig[m * 256 + n];
                }
        }
    }
}

// ---------------- P1: chunk-end states (X fp16 pairs as u32) ----------------
__global__ __launch_bounds__(256) void k_ends(const u32* __restrict__ X,
        const float* __restrict__ ApowRe, const float* __restrict__ ApowIm,
        float2* __restrict__ ends) {
    int p = threadIdx.x;
    int c = blockIdx.x & (NC - 1), b = blockIdx.x >> 7;
    float ar = ApowRe[PD + p], ai = ApowIm[PD + p];    // A^1
    float xr = 0.f, xi = 0.f;
    int mb = b * 32 + (c >> 2);
    int r0 = (c & 3) * 64;
    size_t base = ((size_t)mb * 16 + (p >> 4)) * 4096 + (size_t)r0 * 16 + (p & 15);
    #pragma unroll 8
    for (int i = 0; i < CHUNK; ++i) {
        u32 wd = X[base + (size_t)i * 16];
        union { u32 u; _Float16 h[2]; } cv; cv.u = wd;
        float ur = (float)cv.h[0], ui = (float)cv.h[1];
        float nr2 = fmaf(ar, xr, fmaf(-ai, xi, ur));
        float ni2 = fmaf(ar, xi, fmaf(ai, xr, ui));
        xr = nr2; xi = ni2;
    }
    ends[((size_t)(b * 256 + p)) * NC + c] = make_float2(xr, xi);   // transposed: c contiguous
}

// ---------------- P2: carry scan over chunks (in-place -> exclusive) ----------------
__global__ void k_scan2(float2* __restrict__ ends,
                        const float* __restrict__ ApowRe, const float* __restrict__ ApowIm) {
    int p = threadIdx.x, b = blockIdx.x;
    float Ar = ApowRe[CHUNK * PD + p], Ai = ApowIm[CHUNK * PD + p];  // A^CHUNK
    float2* row = ends + ((size_t)(b * 256 + p)) * NC;
    float cr = 0.f, ci = 0.f;
    #pragma unroll 1
    for (int c0 = 0; c0 < NC; c0 += 8) {
        float2 v[8];
        #pragma unroll
        for (int k = 0; k < 8; ++k) v[k] = row[c0 + k];
        #pragma unroll
        for (int k = 0; k < 8; ++k) {
            row[c0 + k] = make_float2(cr, ci);
            float nr = fmaf(Ar, cr, fmaf(-Ai, ci, v[k].x));
            float ni = fmaf(Ar, ci, fmaf(Ai, cr, v[k].y));
            cr = nr; ci = ni;
        }
    }
}

// ---------------- P3: recompute scan with carry, overwrite X with fp16 state ---------
__global__ __launch_bounds__(256) void k_scan3(u32* __restrict__ X,
        const float* __restrict__ ApowRe, const float* __restrict__ ApowIm,
        const float2* __restrict__ carry) {
    int p = threadIdx.x;
    int c = blockIdx.x & (NC - 1), b = blockIdx.x >> 7;
    float ar = ApowRe[PD + p], ai = ApowIm[PD + p];    // A^1
    float2 cv0 = carry[((size_t)(b * 256 + p)) * NC + c];
    float xr = cv0.x, xi = cv0.y;
    int mb = b * 32 + (c >> 2);
    int r0 = (c & 3) * 64;
    size_t base = ((size_t)mb * 16 + (p >> 4)) * 4096 + (size_t)r0 * 16 + (p & 15);
    #pragma unroll 8
    for (int i = 0; i < CHUNK; ++i) {
        size_t idx = base + (size_t)i * 16;
        union { u32 u; _Float16 h[2]; } cv; cv.u = X[idx];
        float ur = (float)cv.h[0], ui = (float)cv.h[1];
        float nr2 = fmaf(ar, xr, fmaf(-ai, xi, ur));
        float ni2 = fmaf(ar, xi, fmaf(ai, xr, ui));
        xr = nr2; xi = ni2;
        cv.h[0] = (_Float16)xr; cv.h[1] = (_Float16)xi;
        X[idx] = cv.u;
    }
}

// ---------------- launcher ----------------
extern "C" void kernel_launch(void* const* d_in, const int* in_sizes, int n_in,
                              void* d_out, int out_size, void* d_ws, size_t ws_size,
                              hipStream_t stream) {
    const float* sig   = (const float*)d_in[0];
    const float* lre   = (const float*)d_in[1];
    const float* lim   = (const float*)d_in[2];
    const float* B_ri  = (const float*)d_in[3];
    const float* Cre   = (const float*)d_in[4];
    const float* Cim   = (const float*)d_in[5];
    const float* Dv    = (const float*)d_in[6];
    const float* lstep = (const float*)d_in[7];
    float* y = (float*)d_out;
    (void)in_sizes; (void)n_in; (void)out_size; (void)ws_size;

    char* base = (char*)d_ws;
    _Float16* X    = (_Float16*)base; base += (size_t)MROWS * 512 * 2;   // 64 MB
    _Float16* sigh = (_Float16*)base; base += (size_t)MROWS * 256 * 2;   // 32 MB
    _Float16* Bc   = (_Float16*)base; base += (size_t)512 * 256 * 2;
    _Float16* Cc   = (_Float16*)base; base += (size_t)256 * 512 * 2;
    float2* ends   = (float2*)base;   base += (size_t)BATCH * 256 * NC * 8;  // 2 MB
    float* ApowRe  = (float*)base;    base += (size_t)(CHUNK + 1) * PD * 4;
    float* ApowIm  = (float*)base;    base += (size_t)(CHUNK + 1) * PD * 4;
    float* coefRe  = (float*)base;    base += PD * 4;
    float* coefIm  = (float*)base;    base += PD * 4;

    k_setup<<<dim3(1), dim3(PD), 0, stream>>>(lre, lim, lstep, coefRe, coefIm, ApowRe, ApowIm);
    k_bbar<<<dim3(PD), dim3(HD), 0, stream>>>(B_ri, coefRe, coefIm, Bc);
    k_ccat<<<dim3(HD), dim3(PD), 0, stream>>>(Cre, Cim, Cc);
    k_sigh<<<dim3((MROWS * 64) / 256), dim3(256), 0, stream>>>(sig, sigh);
    // G1: X = sigh @ Bcat^T   (M=65536, N=512, K=256) -> 512 blocks
    gemm_f16<8, 2, false><<<dim3(512), dim3(512), 0, stream>>>(
        sigh, Bc, X, nullptr, nullptr, nullptr);
    k_ends<<<dim3(NC * BATCH), dim3(PD), 0, stream>>>((const u32*)X, ApowRe, ApowIm, ends);
    k_scan2<<<dim3(BATCH), dim3(PD), 0, stream>>>(ends, ApowRe, ApowIm);
    k_scan3<<<dim3(NC * BATCH), dim3(PD), 0, stream>>>((u32*)X, ApowRe, ApowIm, ends);
    // G2: y = X @ Ccat^T + D*u  (M=65536, N=256, K=512) -> 256 blocks
    gemm_f16<16, 1, true><<<dim3(256), dim3(512), 0, stream>>>(
        X, Cc, nullptr, y, Dv, sig);
}